// Round 10
// baseline (1135.298 us; speedup 1.0000x reference)
//
#include <hip/hip_runtime.h>
#include <hip/hip_bf16.h>
#include <stdint.h>

// Problem dims
#define BATCH 256
#define SEQ   512
#define INDIM 64
#define H     128
#define RB    4               // batch rows per block (valid C-rows at quad*4, r=0)
#define NTILE (BATCH / RB)    // 64 batch tiles per layer
#define CH    8               // pipeline handoff chunk (steps); 8 so xpre fits regs
#define NCH   (SEQ / CH)

using short8  = __attribute__((ext_vector_type(8))) short;  // 8 bf16 MFMA A/B frag
using float4v = __attribute__((ext_vector_type(4))) float;  // MFMA C/D frag

#define LOG2E 1.4426950408889634f

__device__ __forceinline__ unsigned short f2bf(float f) {
    union { float f; uint32_t u; } v; v.f = f;
    uint32_t u = v.u;
    return (unsigned short)((u + 0x7FFFu + ((u >> 16) & 1u)) >> 16); // RNE
}

__device__ __forceinline__ float fast_exp2(float x) {
#if __has_builtin(__builtin_amdgcn_exp2f)
    return __builtin_amdgcn_exp2f(x);
#else
    return __expf(x * 0.6931471805599453f);
#endif
}
__device__ __forceinline__ float fast_rcp(float x) {
#if __has_builtin(__builtin_amdgcn_rcpf)
    return __builtin_amdgcn_rcpf(x);
#else
    return 1.f / x;
#endif
}
__device__ __forceinline__ float sigmoid_fast(float x) {
    return fast_rcp(1.f + fast_exp2(-LOG2E * x));
}
__device__ __forceinline__ float tanh_fast(float x) {
    return fmaf(-2.f, fast_rcp(1.f + fast_exp2((2.f * LOG2E) * x)), 1.f);
}

// In-step barrier: LDS ordering only (lgkmcnt). Global loads/stores stay in
// flight across it. Full __syncthreads (vmcnt drain) only at producer chunk
// boundaries.
__device__ __forceinline__ void light_barrier() {
    asm volatile("s_waitcnt lgkmcnt(0)\n\ts_barrier" ::: "memory");
}

// ---------------- x fp32 -> bf16 convert (+ flag zeroing) ----------------
// R8 lesson: cvt cannot live in the LSTM step path (forces vmcnt drains).
__global__ void conv_x_kernel(const float* __restrict__ x,
                              unsigned short* __restrict__ xb, int n4,
                              int* __restrict__ flags) {
    int i = blockIdx.x * blockDim.x + threadIdx.x;
    if (blockIdx.x == 0 && threadIdx.x < NTILE) flags[threadIdx.x] = 0;
    if (i >= n4) return;
    float4 f = ((const float4*)x)[i];
    ushort4 o;
    o.x = f2bf(f.x); o.y = f2bf(f.y); o.z = f2bf(f.z); o.w = f2bf(f.w);
    ((ushort4*)xb)[i] = o;
}

// ---------------- fused 2-layer pipelined LSTM + head ----------------
// 128 blocks x 512 threads. Blocks 0..63: layer0 (producer), 64..127:
// layer1 (consumer), paired on batch tile bt via chunked flag handoff
// through global h0sq.
//
// Established constraints:
//  - R2/R7: occupancy & wave-width moves dead (weights force 2 waves/SIMD).
//  - R3: depth-2 h chains verified. R4/R8: no fresh-data loads or cvts on
//    the serial path. R9: moving MFMA issue within the step is neutral —
//    the serial region is saturated at ~1880cy with 32 MFMAs/wave/step.
//
// R10 mechanism (X-PROJECTION HOISTING): Wih·x(t) has NO recurrence — it
// does not belong between barriers. Per chunk (CH=8):
//   BURST (barrier-free, full ILP): compute xpre[s][tT] = bias + Wih·x(t0+s)
//     (scalar element 0 only) for all 8 steps. 4 parallel chains x 8
//     independent steps -> pure MFMA throughput. Producer preloads the whole
//     chunk's x upfront (16 loads, HBM latency paid once); consumer streams
//     h0sq with a dist-2 triple buffer (L2-remote ~400-500cy covered by
//     2x256cy of MFMA issue).
//   SERIAL (8 steps, fully unrolled): ds_read h -> 16 h-MFMAs (two depth-2
//     chains, zero4-seeded) -> g = accA[0]+accB[0]+xpre[i][tT] -> activation
//     -> ds_write -> light_barrier. No global loads at all; serial MFMA
//     count halved (32 -> 16).
// R5 lesson (enforced): xpre/xs/buffers indexed ONLY via fully-unrolled
// constant-trip loops or constant lambda args (always_inline folds them).
template<int KIN, bool IS_PROD>
__device__ __forceinline__ void lstm_body(
    const unsigned short* __restrict__ xin,  // [BATCH][SEQ][KIN] bf16
    const float* __restrict__ Wih,           // [4H][KIN]
    const float* __restrict__ Whh,           // [4H][H]
    const float* __restrict__ b_ih, const float* __restrict__ b_hh,
    unsigned short* __restrict__ outseq,     // producer: [BATCH][SEQ][H] bf16
    const float* __restrict__ W1, const float* __restrict__ b1,
    const float* __restrict__ W2, const float* __restrict__ b2,
    float* __restrict__ out,                 // consumer: [BATCH][3]
    int* flag, int bt)
{
    constexpr int KT  = KIN / 32;
    constexpr int PAD = 132;                 // 66 dwords == 2 mod 32 -> 2-way (free) aliasing
    const int lane = threadIdx.x & 63;
    const int quad = lane >> 4;
    const int l16  = lane & 15;
    const int b0   = bt * RB;
    const int cell = (threadIdx.x >> 6) * 16 + l16;
    const int arow = l16 & 12;               // LDS h row this lane reads (4-lane broadcast)
    const int xrow = b0 + (l16 >> 2);        // batch row this lane loads (duplicated 4x)

    __shared__ short hbuf[2][16][PAD];
    __shared__ float hl[RB][128];            // fp32 h_last (consumer head input)
    __shared__ float mid[RB][65];
    for (int i = threadIdx.x; i < 2 * 16 * PAD; i += 512) ((short*)hbuf)[i] = 0;

    // ---- weight fragments (loaded once, fp32->bf16, persist in registers) ----
    short8 whh_f[4][4];
    short8 wih_f[4][KT];
    float  bias[4];
#pragma unroll
    for (int tT = 0; tT < 4; tT++) {
        const int n = tT * 128 + cell;
#pragma unroll
        for (int kt = 0; kt < 4; kt++) {
            const float* p = Whh + (size_t)n * H + kt * 32 + quad * 8;
            float4 f0 = *(const float4*)p;
            float4 f1 = *(const float4*)(p + 4);
            short8 s;
            s[0]=f2bf(f0.x); s[1]=f2bf(f0.y); s[2]=f2bf(f0.z); s[3]=f2bf(f0.w);
            s[4]=f2bf(f1.x); s[5]=f2bf(f1.y); s[6]=f2bf(f1.z); s[7]=f2bf(f1.w);
            whh_f[tT][kt] = s;
        }
#pragma unroll
        for (int kt = 0; kt < KT; kt++) {
            const float* p = Wih + (size_t)n * KIN + kt * 32 + quad * 8;
            float4 f0 = *(const float4*)p;
            float4 f1 = *(const float4*)(p + 4);
            short8 s;
            s[0]=f2bf(f0.x); s[1]=f2bf(f0.y); s[2]=f2bf(f0.z); s[3]=f2bf(f0.w);
            s[4]=f2bf(f1.x); s[5]=f2bf(f1.y); s[6]=f2bf(f1.z); s[7]=f2bf(f1.w);
            wih_f[tT][kt] = s;
        }
        bias[tT] = b_ih[n] + b_hh[n];
    }

    // persistent zero seed (R5 pin: block per-step rematerialization)
    float4v zero4 = (float4v){0.f, 0.f, 0.f, 0.f};
    asm volatile("" : "+v"(zero4));

    float c0 = 0.f;                          // this lane's single cell state

    const unsigned short* xq = xin + ((size_t)xrow * SEQ) * KIN + quad * 8;
    unsigned short* op = nullptr;
    if (IS_PROD)
        op = outseq + ((size_t)(b0 + quad) * SEQ) * H + cell;

    float xpre[CH][4];                       // chunk x-partials (incl bias); 32 VGPRs
    __syncthreads();                         // hbuf zero-init visible

    // Burst sub-step: xpre[s] = bias + Wih·x(t0+s). s is a constant at every
    // call site (always_inline folds it) -> static indexing.
    auto bcompute = [&](int s, short8 (&use)[KT]) __attribute__((always_inline)) {
        float4v a[4];
#pragma unroll
        for (int tT = 0; tT < 4; tT++)
            a[tT] = __builtin_amdgcn_mfma_f32_16x16x32_bf16(use[0], wih_f[tT][0], zero4, 0, 0, 0);
#pragma unroll
        for (int tT = 0; tT < 4; tT++)
            a[tT] = __builtin_amdgcn_mfma_f32_16x16x32_bf16(use[1], wih_f[tT][1], a[tT], 0, 0, 0);
        if constexpr (KT == 4) {
#pragma unroll
            for (int tT = 0; tT < 4; tT++)
                a[tT] = __builtin_amdgcn_mfma_f32_16x16x32_bf16(use[2], wih_f[tT][2], a[tT], 0, 0, 0);
#pragma unroll
            for (int tT = 0; tT < 4; tT++)
                a[tT] = __builtin_amdgcn_mfma_f32_16x16x32_bf16(use[3], wih_f[tT][3], a[tT], 0, 0, 0);
        }
#pragma unroll
        for (int tT = 0; tT < 4; tT++)
            xpre[s][tT] = a[tT][0] + bias[tT];
    };

    // Serial step: h-projection only. i constant at call sites.
    auto sstep = [&](int i, int t) __attribute__((always_inline)) {
        const int CUR = i & 1;               // t0 even -> t&1 == i&1
        short8 ha[4];
#pragma unroll
        for (int kt = 0; kt < 4; kt++)
            ha[kt] = *(const short8*)&hbuf[CUR][arow][kt * 32 + quad * 8];

        float4v accA[4], accB[4];            // two depth-2 chains
#pragma unroll
        for (int tT = 0; tT < 4; tT++)
            accA[tT] = __builtin_amdgcn_mfma_f32_16x16x32_bf16(ha[0], whh_f[tT][0], zero4, 0, 0, 0);
#pragma unroll
        for (int tT = 0; tT < 4; tT++)
            accB[tT] = __builtin_amdgcn_mfma_f32_16x16x32_bf16(ha[2], whh_f[tT][2], zero4, 0, 0, 0);
#pragma unroll
        for (int tT = 0; tT < 4; tT++)
            accA[tT] = __builtin_amdgcn_mfma_f32_16x16x32_bf16(ha[1], whh_f[tT][1], accA[tT], 0, 0, 0);
#pragma unroll
        for (int tT = 0; tT < 4; tT++)
            accB[tT] = __builtin_amdgcn_mfma_f32_16x16x32_bf16(ha[3], whh_f[tT][3], accB[tT], 0, 0, 0);

        float g0 = (accA[0][0] + accB[0][0]) + xpre[i][0];
        float g1 = (accA[1][0] + accB[1][0]) + xpre[i][1];
        float g2 = (accA[2][0] + accB[2][0]) + xpre[i][2];
        float g3 = (accA[3][0] + accB[3][0]) + xpre[i][3];

        float si = sigmoid_fast(g0);
        float sf = sigmoid_fast(g1);
        float tg = tanh_fast(g2);
        float so = sigmoid_fast(g3);
        c0 = fmaf(sf, c0, si * tg);
        float h = so * tanh_fast(c0);
        uint32_t hp;
        asm("v_cvt_pk_bf16_f32 %0, %1, %2" : "=v"(hp) : "v"(h), "v"(h));
        hbuf[CUR ^ 1][quad * 4][cell] = (short)(hp & 0xffffu);
        if (IS_PROD) {
            *op = (unsigned short)(hp & 0xffffu);  // fire-and-forget
            op += H;
        } else if (t == SEQ - 1) {
            hl[quad][cell] = h;
        }
        light_barrier();
    };

    for (int ch = 0; ch < NCH; ch++) {
        const int t0 = ch * CH;
        if constexpr (!IS_PROD) {
            if (threadIdx.x == 0) {
                while (__hip_atomic_load(flag, __ATOMIC_RELAXED, __HIP_MEMORY_SCOPE_AGENT) <= ch)
                    __builtin_amdgcn_s_sleep(2);
                (void)__hip_atomic_load(flag, __ATOMIC_ACQUIRE, __HIP_MEMORY_SCOPE_AGENT);
            }
            __syncthreads();
        }

        // ---------------- burst: x-projection for the whole chunk ----------
        if constexpr (IS_PROD) {
            // preload ALL chunk x frags (CH*KT=16 b128 loads; HBM latency
            // paid once, then pure MFMA throughput)
            short8 xs[CH][KT];
#pragma unroll
            for (int s = 0; s < CH; s++)
#pragma unroll
                for (int kt = 0; kt < KT; kt++)
                    xs[s][kt] = *(const short8*)(xq + (size_t)(t0 + s) * KIN + kt * 32);
#pragma unroll
            for (int s = 0; s < CH; s++)
                bcompute(s, xs[s]);
        } else {
            // dist-2 triple-buffer stream (L2-remote h0sq ~400-500cy covered
            // by 2 x 256cy of burst MFMA issue)
            short8 bufA[KT], bufB[KT], bufC[KT];
#pragma unroll
            for (int kt = 0; kt < KT; kt++) {
                bufA[kt] = *(const short8*)(xq + (size_t)(t0 + 0) * KIN + kt * 32);
                bufB[kt] = *(const short8*)(xq + (size_t)(t0 + 1) * KIN + kt * 32);
            }
            auto bload = [&](short8 (&dst)[KT], int s) __attribute__((always_inline)) {
#pragma unroll
                for (int kt = 0; kt < KT; kt++)
                    dst[kt] = *(const short8*)(xq + (size_t)(t0 + s) * KIN + kt * 32);
            };
            bload(bufC, t0 >= 0 ? 2 : 2);    // s=2
            bcompute(0, bufA);
            bload(bufA, 3);  bcompute(1, bufB);
            bload(bufB, 4);  bcompute(2, bufC);
            bload(bufC, 5);  bcompute(3, bufA);
            bload(bufA, 6);  bcompute(4, bufB);
            bload(bufB, 7);  bcompute(5, bufC);
            bcompute(6, bufA);
            bcompute(7, bufB);
        }

        // ---------------- serial: h-recurrence only ------------------------
#pragma unroll
        for (int i = 0; i < CH; i++)
            sstep(i, t0 + i);

        if constexpr (IS_PROD) {
            __syncthreads();                 // vmcnt drain (h0sq stores) for release
            if (threadIdx.x == 0)
                __hip_atomic_fetch_add(flag, 1, __ATOMIC_RELEASE, __HIP_MEMORY_SCOPE_AGENT);
        }
    }

    if (!IS_PROD) {
        // ---- MLP head for this block's RB rows (hl visible via last barrier)
        if (threadIdx.x < RB * 64) {
            const int row = threadIdx.x >> 6, j = threadIdx.x & 63;
            float s = b1[j];
            const float* wr = W1 + (size_t)j * 128;
#pragma unroll 8
            for (int k = 0; k < 128; k++) s = fmaf(hl[row][k], wr[k], s);
            mid[row][j] = fmaxf(s, 0.f);
        }
        __syncthreads();
        if (threadIdx.x < RB * 3) {
            const int row = threadIdx.x / 3, k = threadIdx.x - row * 3;
            float o = b2[k];
            const float* wr = W2 + (size_t)k * 64;
#pragma unroll 8
            for (int j = 0; j < 64; j++) o = fmaf(mid[row][j], wr[j], o);
            out[(size_t)(b0 + row) * 3 + k] = o;
        }
    }
}

__global__ __launch_bounds__(512, 2)
void lstm_fused_kernel(const unsigned short* __restrict__ xb,
                       const float* __restrict__ Wih0, const float* __restrict__ Whh0,
                       const float* __restrict__ bih0, const float* __restrict__ bhh0,
                       const float* __restrict__ Wih1, const float* __restrict__ Whh1,
                       const float* __restrict__ bih1, const float* __restrict__ bhh1,
                       unsigned short* __restrict__ h0sq,
                       const float* __restrict__ W1, const float* __restrict__ b1,
                       const float* __restrict__ W2, const float* __restrict__ b2,
                       float* __restrict__ out,
                       int* __restrict__ flags)
{
    const int bt = blockIdx.x & (NTILE - 1);
    if (blockIdx.x < NTILE)
        lstm_body<64,  true >(xb,   Wih0, Whh0, bih0, bhh0, h0sq,
                              W1, b1, W2, b2, out, flags + bt, bt);
    else
        lstm_body<128, false>(h0sq, Wih1, Whh1, bih1, bhh1, nullptr,
                              W1, b1, W2, b2, out, flags + bt, bt);
}

extern "C" void kernel_launch(void* const* d_in, const int* in_sizes, int n_in,
                              void* d_out, int out_size, void* d_ws, size_t ws_size,
                              hipStream_t stream) {
    const float* x     = (const float*)d_in[0];
    const float* W_ih0 = (const float*)d_in[1];
    const float* W_hh0 = (const float*)d_in[2];
    const float* b_ih0 = (const float*)d_in[3];
    const float* b_hh0 = (const float*)d_in[4];
    const float* W_ih1 = (const float*)d_in[5];
    const float* W_hh1 = (const float*)d_in[6];
    const float* b_ih1 = (const float*)d_in[7];
    const float* b_hh1 = (const float*)d_in[8];
    const float* W1    = (const float*)d_in[9];
    const float* b1    = (const float*)d_in[10];
    const float* W2    = (const float*)d_in[11];
    const float* b2    = (const float*)d_in[12];
    float* out = (float*)d_out;

    // workspace: xb bf16[256*512*64] @0 (16 MB); h0sq bf16[256*512*128] @16 MB (32 MB); flags @48 MB
    char* ws = (char*)d_ws;
    unsigned short* xb    = (unsigned short*)ws;
    unsigned short* h0sq  = (unsigned short*)(ws + 16777216);
    int*            flags = (int*)(ws + 50331648);

    conv_x_kernel<<<8192, 256, 0, stream>>>(x, xb, (BATCH * SEQ * INDIM) / 4, flags);
    lstm_fused_kernel<<<2 * NTILE, 512, 0, stream>>>(xb, W_ih0, W_hh0, b_ih0, b_hh0,
                                                     W_ih1, W_hh1, b_ih1, b_hh1,
                                                     h0sq, W1, b1, W2, b2, out, flags);
}

// Round 11
// 488.678 us; speedup vs baseline: 2.3232x; 2.3232x over previous
//
#include <hip/hip_runtime.h>
#include <hip/hip_bf16.h>
#include <stdint.h>

// Problem dims
#define BATCH 256
#define SEQ   512
#define INDIM 64
#define H     128
#define RB    4               // batch rows per block (valid C-rows at quad*4, r=0)
#define NTILE (BATCH / RB)    // 64 batch tiles per layer
#define CH    8               // chunk = 2 time-bursts of 4 steps
#define NCH   (SEQ / CH)

using short8  = __attribute__((ext_vector_type(8))) short;  // 8 bf16 MFMA A/B frag
using float4v = __attribute__((ext_vector_type(4))) float;  // MFMA C/D frag

#define LOG2E 1.4426950408889634f

__device__ __forceinline__ unsigned short f2bf(float f) {
    union { float f; uint32_t u; } v; v.f = f;
    uint32_t u = v.u;
    return (unsigned short)((u + 0x7FFFu + ((u >> 16) & 1u)) >> 16); // RNE
}

__device__ __forceinline__ float fast_exp2(float x) {
#if __has_builtin(__builtin_amdgcn_exp2f)
    return __builtin_amdgcn_exp2f(x);
#else
    return __expf(x * 0.6931471805599453f);
#endif
}
__device__ __forceinline__ float fast_rcp(float x) {
#if __has_builtin(__builtin_amdgcn_rcpf)
    return __builtin_amdgcn_rcpf(x);
#else
    return 1.f / x;
#endif
}
__device__ __forceinline__ float sigmoid_fast(float x) {
    return fast_rcp(1.f + fast_exp2(-LOG2E * x));
}
__device__ __forceinline__ float tanh_fast(float x) {
    return fmaf(-2.f, fast_rcp(1.f + fast_exp2((2.f * LOG2E) * x)), 1.f);
}

// In-step barrier: LDS ordering only (lgkmcnt). Global loads/stores stay in
// flight across it. Full __syncthreads (vmcnt drain) only at producer chunk
// boundaries.
__device__ __forceinline__ void light_barrier() {
    asm volatile("s_waitcnt lgkmcnt(0)\n\ts_barrier" ::: "memory");
}

// ---------------- x fp32 -> bf16 convert (+ flag zeroing) ----------------
// R8 lesson: cvt cannot live in the LSTM step path (forces vmcnt drains).
__global__ void conv_x_kernel(const float* __restrict__ x,
                              unsigned short* __restrict__ xb, int n4,
                              int* __restrict__ flags) {
    int i = blockIdx.x * blockDim.x + threadIdx.x;
    if (blockIdx.x == 0 && threadIdx.x < NTILE) flags[threadIdx.x] = 0;
    if (i >= n4) return;
    float4 f = ((const float4*)x)[i];
    ushort4 o;
    o.x = f2bf(f.x); o.y = f2bf(f.y); o.z = f2bf(f.z); o.w = f2bf(f.w);
    ((ushort4*)xb)[i] = o;
}

// ---------------- fused 2-layer pipelined LSTM + head ----------------
// 128 blocks x 512 threads. Blocks 0..63: layer0 (producer), 64..127:
// layer1 (consumer), paired on batch tile bt via chunked flag handoff
// through global h0sq. (R5 skeleton: RB=4, same sync discipline.)
//
// Established constraints:
//  - R2/R7: occupancy & wave-width moves dead. R4/R8: no fresh loads/cvts on
//    the serial path. R9: rearranging issue within the step is neutral.
//  - R10 (spilled): x-hoisting per-step needed 64-96 persistent staging regs
//    -> scratch (WRITE 110MB). Concept untested, staging cost fatal.
//  - Plateau cause: per-SIMD mandatory MFMA pipe time = 2 waves x 32 MFMA x
//    16cy = ~1024cy/step under a ~1880cy measured step.
//
// R11 mechanism (TIME-BATCHED x-projection): the x-projection is
// recurrence-free across TIME, and the MFMA A-operand has 16 rows of which
// RB=4 designs use 4 with 4x duplication. Map A-rows to (batch b0+(r>>2),
// time t0+(r&3)): ONE burst of 4(gates) x KT MFMAs computes bias + Wih*x for
// FOUR steps. C-layout lands exactly as needed: lane(quad,l16)'s
// acc[gate][reg] = x-partial for (batch b0+quad, time t0+reg, cell l16) —
// the burst output IS xpre, in registers, no extraction. Staging = af[KT]
// transient (16-32 VGPR); xpre = xpA[4]+xpB[4] float4v = 32 VGPR.
// Serial step: ds_read h -> 16 h-MFMAs (two depth-2 chains) ->
// g = accA[0]+accB[0]+xp[gate][i&3] -> act -> write -> light_barrier.
// Per-wave serial MFMA halves (32 -> 16); burst adds 4-8 MFMAs/4 steps.
// Peak consumer live set ~243 < 256 (spill tripwire: WRITE_SIZE > 40MB).
// R5 lesson (enforced): all register arrays statically indexed via fully
// unrolled loops; i&3 / i<4 fold at compile time in the unrolled serial loop.
template<int KIN, bool IS_PROD>
__device__ __forceinline__ void lstm_body(
    const unsigned short* __restrict__ xin,  // [BATCH][SEQ][KIN] bf16
    const float* __restrict__ Wih,           // [4H][KIN]
    const float* __restrict__ Whh,           // [4H][H]
    const float* __restrict__ b_ih, const float* __restrict__ b_hh,
    unsigned short* __restrict__ outseq,     // producer: [BATCH][SEQ][H] bf16
    const float* __restrict__ W1, const float* __restrict__ b1,
    const float* __restrict__ W2, const float* __restrict__ b2,
    float* __restrict__ out,                 // consumer: [BATCH][3]
    int* flag, int bt)
{
    constexpr int KT  = KIN / 32;
    constexpr int PAD = 132;                 // 66 dwords == 2 mod 32 -> 2-way (free) aliasing
    const int lane = threadIdx.x & 63;
    const int quad = lane >> 4;
    const int l16  = lane & 15;
    const int b0   = bt * RB;
    const int cell = (threadIdx.x >> 6) * 16 + l16;
    const int arow = l16 & 12;               // LDS h row this lane reads (4-lane broadcast)

    __shared__ short hbuf[2][16][PAD];
    __shared__ float hl[RB][128];            // fp32 h_last (consumer head input)
    __shared__ float mid[RB][65];
    for (int i = threadIdx.x; i < 2 * 16 * PAD; i += 512) ((short*)hbuf)[i] = 0;

    // ---- weight fragments (loaded once, fp32->bf16, persist in registers) ----
    short8 whh_f[4][4];
    short8 wih_f[4][KT];
    float  bias[4];
#pragma unroll
    for (int tT = 0; tT < 4; tT++) {
        const int n = tT * 128 + cell;
#pragma unroll
        for (int kt = 0; kt < 4; kt++) {
            const float* p = Whh + (size_t)n * H + kt * 32 + quad * 8;
            float4 f0 = *(const float4*)p;
            float4 f1 = *(const float4*)(p + 4);
            short8 s;
            s[0]=f2bf(f0.x); s[1]=f2bf(f0.y); s[2]=f2bf(f0.z); s[3]=f2bf(f0.w);
            s[4]=f2bf(f1.x); s[5]=f2bf(f1.y); s[6]=f2bf(f1.z); s[7]=f2bf(f1.w);
            whh_f[tT][kt] = s;
        }
#pragma unroll
        for (int kt = 0; kt < KT; kt++) {
            const float* p = Wih + (size_t)n * KIN + kt * 32 + quad * 8;
            float4 f0 = *(const float4*)p;
            float4 f1 = *(const float4*)(p + 4);
            short8 s;
            s[0]=f2bf(f0.x); s[1]=f2bf(f0.y); s[2]=f2bf(f0.z); s[3]=f2bf(f0.w);
            s[4]=f2bf(f1.x); s[5]=f2bf(f1.y); s[6]=f2bf(f1.z); s[7]=f2bf(f1.w);
            wih_f[tT][kt] = s;
        }
        bias[tT] = b_ih[n] + b_hh[n];
    }

    // persistent seeds (R5 pin: block per-step/burst rematerialization)
    float4v bias4[4], zero4;
#pragma unroll
    for (int tT = 0; tT < 4; tT++)
        bias4[tT] = (float4v){bias[tT], bias[tT], bias[tT], bias[tT]};
    zero4 = (float4v){0.f, 0.f, 0.f, 0.f};
    asm volatile("" : "+v"(bias4[0]), "+v"(bias4[1]), "+v"(bias4[2]),
                      "+v"(bias4[3]), "+v"(zero4));

    float c0 = 0.f;                          // this lane's single cell state

    // Burst x base: A-row l16 <-> (batch b0+(l16>>2), time offset l16&3).
    const unsigned short* xq = xin +
        (((size_t)(b0 + (l16 >> 2)) * SEQ) + (l16 & 3)) * KIN + quad * 8;
    unsigned short* op = nullptr;
    if (IS_PROD)
        op = outseq + ((size_t)(b0 + quad) * SEQ) * H + cell;

    __syncthreads();                         // hbuf zero-init visible

    // Serial step: h-recurrence only. i is constant at every call site
    // (fully unrolled chunk loop) -> xp[tT][i&3] is statically indexed.
    auto sstep = [&](int i, int t, const float4v (&xp)[4]) __attribute__((always_inline)) {
        const int CUR = i & 1;               // t0 even -> (t0+i)&1 == i&1
        short8 ha[4];
#pragma unroll
        for (int kt = 0; kt < 4; kt++)
            ha[kt] = *(const short8*)&hbuf[CUR][arow][kt * 32 + quad * 8];

        float4v accA[4], accB[4];            // two depth-2 chains
#pragma unroll
        for (int tT = 0; tT < 4; tT++)
            accA[tT] = __builtin_amdgcn_mfma_f32_16x16x32_bf16(ha[0], whh_f[tT][0], zero4, 0, 0, 0);
#pragma unroll
        for (int tT = 0; tT < 4; tT++)
            accB[tT] = __builtin_amdgcn_mfma_f32_16x16x32_bf16(ha[2], whh_f[tT][2], zero4, 0, 0, 0);
#pragma unroll
        for (int tT = 0; tT < 4; tT++)
            accA[tT] = __builtin_amdgcn_mfma_f32_16x16x32_bf16(ha[1], whh_f[tT][1], accA[tT], 0, 0, 0);
#pragma unroll
        for (int tT = 0; tT < 4; tT++)
            accB[tT] = __builtin_amdgcn_mfma_f32_16x16x32_bf16(ha[3], whh_f[tT][3], accB[tT], 0, 0, 0);

        const int r = i & 3;                 // time slot within burst group
        float g0 = (accA[0][0] + accB[0][0]) + xp[0][r];
        float g1 = (accA[1][0] + accB[1][0]) + xp[1][r];
        float g2 = (accA[2][0] + accB[2][0]) + xp[2][r];
        float g3 = (accA[3][0] + accB[3][0]) + xp[3][r];

        float si = sigmoid_fast(g0);
        float sf = sigmoid_fast(g1);
        float tg = tanh_fast(g2);
        float so = sigmoid_fast(g3);
        c0 = fmaf(sf, c0, si * tg);
        float h = so * tanh_fast(c0);
        uint32_t hp;
        asm("v_cvt_pk_bf16_f32 %0, %1, %2" : "=v"(hp) : "v"(h), "v"(h));
        hbuf[CUR ^ 1][quad * 4][cell] = (short)(hp & 0xffffu);
        if (IS_PROD) {
            *op = (unsigned short)(hp & 0xffffu);  // fire-and-forget
            op += H;
        } else if (t == SEQ - 1) {
            hl[quad][cell] = h;
        }
        light_barrier();
    };

    for (int ch = 0; ch < NCH; ch++) {
        const int t0 = ch * CH;
        if constexpr (!IS_PROD) {
            if (threadIdx.x == 0) {
                while (__hip_atomic_load(flag, __ATOMIC_RELAXED, __HIP_MEMORY_SCOPE_AGENT) <= ch)
                    __builtin_amdgcn_s_sleep(2);
                (void)__hip_atomic_load(flag, __ATOMIC_ACQUIRE, __HIP_MEMORY_SCOPE_AGENT);
            }
            __syncthreads();
        }

        // ---- time-bursts: x-partials for steps t0..t0+3 and t0+4..t0+7 ----
        // Both load sets issued before any MFMA (loads pipeline; MFMA B
        // overlaps load B completion). af* die before the serial phase.
        float4v xpA[4], xpB[4];
        {
            short8 afA[KT], afB[KT];
#pragma unroll
            for (int kt = 0; kt < KT; kt++)
                afA[kt] = *(const short8*)(xq + (size_t)t0 * KIN + kt * 32);
#pragma unroll
            for (int kt = 0; kt < KT; kt++)
                afB[kt] = *(const short8*)(xq + (size_t)(t0 + 4) * KIN + kt * 32);
#pragma unroll
            for (int tT = 0; tT < 4; tT++)
                xpA[tT] = __builtin_amdgcn_mfma_f32_16x16x32_bf16(afA[0], wih_f[tT][0], bias4[tT], 0, 0, 0);
#pragma unroll
            for (int kt = 1; kt < KT; kt++)
#pragma unroll
                for (int tT = 0; tT < 4; tT++)
                    xpA[tT] = __builtin_amdgcn_mfma_f32_16x16x32_bf16(afA[kt], wih_f[tT][kt], xpA[tT], 0, 0, 0);
#pragma unroll
            for (int tT = 0; tT < 4; tT++)
                xpB[tT] = __builtin_amdgcn_mfma_f32_16x16x32_bf16(afB[0], wih_f[tT][0], bias4[tT], 0, 0, 0);
#pragma unroll
            for (int kt = 1; kt < KT; kt++)
#pragma unroll
                for (int tT = 0; tT < 4; tT++)
                    xpB[tT] = __builtin_amdgcn_mfma_f32_16x16x32_bf16(afB[kt], wih_f[tT][kt], xpB[tT], 0, 0, 0);
        }

        // ---- serial: h-recurrence only (16 MFMAs/step) --------------------
#pragma unroll
        for (int i = 0; i < 4; i++)
            sstep(i, t0 + i, xpA);
#pragma unroll
        for (int i = 4; i < CH; i++)
            sstep(i, t0 + i, xpB);

        if constexpr (IS_PROD) {
            __syncthreads();                 // vmcnt drain (h0sq stores) for release
            if (threadIdx.x == 0)
                __hip_atomic_fetch_add(flag, 1, __ATOMIC_RELEASE, __HIP_MEMORY_SCOPE_AGENT);
        }
    }

    if (!IS_PROD) {
        // ---- MLP head for this block's RB rows (hl visible via last barrier)
        if (threadIdx.x < RB * 64) {
            const int row = threadIdx.x >> 6, j = threadIdx.x & 63;
            float s = b1[j];
            const float* wr = W1 + (size_t)j * 128;
#pragma unroll 8
            for (int k = 0; k < 128; k++) s = fmaf(hl[row][k], wr[k], s);
            mid[row][j] = fmaxf(s, 0.f);
        }
        __syncthreads();
        if (threadIdx.x < RB * 3) {
            const int row = threadIdx.x / 3, k = threadIdx.x - row * 3;
            float o = b2[k];
            const float* wr = W2 + (size_t)k * 64;
#pragma unroll 8
            for (int j = 0; j < 64; j++) o = fmaf(mid[row][j], wr[j], o);
            out[(size_t)(b0 + row) * 3 + k] = o;
        }
    }
}

__global__ __launch_bounds__(512, 2)
void lstm_fused_kernel(const unsigned short* __restrict__ xb,
                       const float* __restrict__ Wih0, const float* __restrict__ Whh0,
                       const float* __restrict__ bih0, const float* __restrict__ bhh0,
                       const float* __restrict__ Wih1, const float* __restrict__ Whh1,
                       const float* __restrict__ bih1, const float* __restrict__ bhh1,
                       unsigned short* __restrict__ h0sq,
                       const float* __restrict__ W1, const float* __restrict__ b1,
                       const float* __restrict__ W2, const float* __restrict__ b2,
                       float* __restrict__ out,
                       int* __restrict__ flags)
{
    const int bt = blockIdx.x & (NTILE - 1);
    if (blockIdx.x < NTILE)
        lstm_body<64,  true >(xb,   Wih0, Whh0, bih0, bhh0, h0sq,
                              W1, b1, W2, b2, out, flags + bt, bt);
    else
        lstm_body<128, false>(h0sq, Wih1, Whh1, bih1, bhh1, nullptr,
                              W1, b1, W2, b2, out, flags + bt, bt);
}

extern "C" void kernel_launch(void* const* d_in, const int* in_sizes, int n_in,
                              void* d_out, int out_size, void* d_ws, size_t ws_size,
                              hipStream_t stream) {
    const float* x     = (const float*)d_in[0];
    const float* W_ih0 = (const float*)d_in[1];
    const float* W_hh0 = (const float*)d_in[2];
    const float* b_ih0 = (const float*)d_in[3];
    const float* b_hh0 = (const float*)d_in[4];
    const float* W_ih1 = (const float*)d_in[5];
    const float* W_hh1 = (const float*)d_in[6];
    const float* b_ih1 = (const float*)d_in[7];
    const float* b_hh1 = (const float*)d_in[8];
    const float* W1    = (const float*)d_in[9];
    const float* b1    = (const float*)d_in[10];
    const float* W2    = (const float*)d_in[11];
    const float* b2    = (const float*)d_in[12];
    float* out = (float*)d_out;

    // workspace: xb bf16[256*512*64] @0 (16 MB); h0sq bf16[256*512*128] @16 MB (32 MB); flags @48 MB
    char* ws = (char*)d_ws;
    unsigned short* xb    = (unsigned short*)ws;
    unsigned short* h0sq  = (unsigned short*)(ws + 16777216);
    int*            flags = (int*)(ws + 50331648);

    conv_x_kernel<<<8192, 256, 0, stream>>>(x, xb, (BATCH * SEQ * INDIM) / 4, flags);
    lstm_fused_kernel<<<2 * NTILE, 512, 0, stream>>>(xb, W_ih0, W_hh0, b_ih0, b_hh0,
                                                     W_ih1, W_hh1, b_ih1, b_hh1,
                                                     h0sq, W1, b1, W2, b2, out, flags);
}